// Round 5
// baseline (95.039 us; speedup 1.0000x reference)
//
#include <hip/hip_runtime.h>
#include <math.h>

// QuantumConv: per-pixel 6-qubit circuit collapses to 6 real symmetric 8x8
// quadratic forms q_w = r^T G_w r (subspace trick: wires 3-5 start at |0>,
// circuit unitary depends only on `weights`).
//
// R5: SINGLE kernel. Each block redundantly builds the packed S[6][36]
// (diag x1 / off-diag x2) as a phase-0 prologue: 4 waves x 2 subspace
// columns via register/shfl butterfly (overlapped with the x/fcw global
// loads issued first), then a 216-thread reduction into LDS. Removes the
// build_G dispatch, its graph edge, and the d_ws round-trip (~3-4us).

#define HP 112   // low-res H (=224/2)
#define WP 112

static __device__ const unsigned char TRI_A[36] = {
    0,0,0,0,0,0,0,0, 1,1,1,1,1,1,1, 2,2,2,2,2,2, 3,3,3,3,3, 4,4,4,4, 5,5,5, 6,6, 7};
static __device__ const unsigned char TRI_B[36] = {
    0,1,2,3,4,5,6,7, 1,2,3,4,5,6,7, 2,3,4,5,6,7, 3,4,5,6,7, 4,5,6,7, 5,6,7, 6,7, 7};

// Block: batch b, 16(oh) x 32(ow) output tile -> needs 10 x 18 low-res y tile.
__global__ __launch_bounds__(256) void fused(
    const float* __restrict__ x, const float* __restrict__ wts,
    const float* __restrict__ fcw, const float* __restrict__ fcb,
    const float* __restrict__ lng, const float* __restrict__ lnb,
    float* __restrict__ out) {

    __shared__ float  U[24][8];          // per-gate 2x2 complex: U00 U01 U10 U11
    __shared__ float2 cs[64][9];         // V[s][a] (+1 pad)
    __shared__ __align__(16) float Ss[216];
    __shared__ float fcwS[96], fcbS[16], lngS[16], lnbS[16];
    __shared__ float yS[16][10][18];     // [c][row][col]

    int tid  = threadIdx.x;
    int lane = tid & 63, wv = tid >> 6;  // wave wv owns subspace cols wv, wv+4
    int b    = blockIdx.z;
    int ow0  = blockIdx.x * 32, oh0 = blockIdx.y * 16;
    int w0   = blockIdx.x * 16, k0  = blockIdx.y * 8;   // low-res tile origin

    // ---- A: issue global loads early (latency hides under the sim) ----
    float2 xr[3][2];
    int pr = tid / 18, pc = tid % 18;
    if (tid < 180) {
        int ih = min(max(k0 - 1 + pr, 0), HP - 1);
        int iw = min(max(w0 - 1 + pc, 0), WP - 1);
        #pragma unroll
        for (int c = 0; c < 3; ++c) {
            const float2* px = reinterpret_cast<const float2*>(
                x + (((b*3 + c)*224 + 2*ih)*224 + 2*iw));
            xr[c][0] = px[0]; xr[c][1] = px[112];
        }
    }
    for (int i = tid; i < 96; i += 256) fcwS[i] = fcw[i];
    if (tid < 16) { fcbS[tid] = fcb[tid]; lngS[tid] = lng[tid]; lnbS[tid] = lnb[tid]; }

    if (tid < 24) {   // gate matrices: Rot(phi, theta, omega)
        float phi = wts[tid*3+0], th = wts[tid*3+1], om = wts[tid*3+2];
        float cth, sth, cap, sap, cam, sam;
        __sincosf(0.5f*th, &sth, &cth);
        __sincosf(0.5f*(phi+om), &sap, &cap);   // ep = cap - i*sap
        __sincosf(0.5f*(phi-om), &sam, &cam);   // em = cam - i*sam
        U[tid][0] =  cap*cth; U[tid][1] = -sap*cth;   // U00 = ep*c
        U[tid][2] = -cam*sth; U[tid][3] = -sam*sth;   // U01 = -conj(em)*s
        U[tid][4] =  cam*sth; U[tid][5] = -sam*sth;   // U10 = em*s
        U[tid][6] =  cap*cth; U[tid][7] =  sap*cth;   // U11 = conj(ep)*c
    }
    __syncthreads();

    // ---- B: circuit sim, register/shfl butterfly; lane = state index ----
    float2 v0 = make_float2((lane == (wv << 3))       ? 1.0f : 0.0f, 0.0f);
    float2 v1 = make_float2((lane == ((wv + 4) << 3)) ? 1.0f : 0.0f, 0.0f);

    for (int l = 0; l < 4; ++l) {
        for (int w = 0; w < 6; ++w) {     // rotations (wire 0 = MSB)
            int g = l*6 + w, m = 1 << (5 - w);
            bool hi = (lane & m) != 0;
            float csr = hi ? U[g][6] : U[g][0], csi = hi ? U[g][7] : U[g][1];
            float cpr = hi ? U[g][4] : U[g][2], cpi = hi ? U[g][5] : U[g][3];
            float p0x = __shfl_xor(v0.x, m), p0y = __shfl_xor(v0.y, m);
            float p1x = __shfl_xor(v1.x, m), p1y = __shfl_xor(v1.y, m);
            v0 = make_float2(csr*v0.x - csi*v0.y + cpr*p0x - cpi*p0y,
                             csr*v0.y + csi*v0.x + cpr*p0y + cpi*p0x);
            v1 = make_float2(csr*v1.x - csi*v1.y + cpr*p1x - cpi*p1y,
                             csr*v1.y + csi*v1.x + cpr*p1y + cpi*p1x);
        }
        int r = l % 5 + 1;                // CNOT ring
        for (int w = 0; w < 6; ++w) {
            int mc = 1 << (5 - w), mt = 1 << (5 - ((w + r) % 6));
            float p0x = __shfl_xor(v0.x, mt), p0y = __shfl_xor(v0.y, mt);
            float p1x = __shfl_xor(v1.x, mt), p1y = __shfl_xor(v1.y, mt);
            if (lane & mc) { v0 = make_float2(p0x, p0y); v1 = make_float2(p1x, p1y); }
        }
    }
    cs[lane][wv]     = v0;
    cs[lane][wv + 4] = v1;
    __syncthreads();

    // ---- C: reduce to packed symmetric S (diag x1, off-diag x2) ----
    // G_w[a][b] = Re( i^(pop(a)-pop(b)) * sum_s z_w(s) conj(V[s,a]) V[s,b] )
    if (tid < 216) {
        int w = tid / 36, idx = tid - 36*w;
        int a = TRI_A[idx], bb = TRI_B[idx];
        int mw = 1 << (5 - w);
        float re = 0.f, im = 0.f;
        #pragma unroll 8
        for (int s = 0; s < 64; ++s) {
            float z = (s & mw) ? -1.f : 1.f;
            float2 va = cs[s][a], vb = cs[s][bb];
            re += z * (va.x*vb.x + va.y*vb.y);
            im += z * (va.x*vb.y - va.y*vb.x);
        }
        int d = (__popc(a) - __popc(bb)) & 3;   // conj(f_a)*f_b = i^d
        float g = (d == 0) ? re : (d == 1) ? -im : (d == 2) ? -re : im;
        Ss[tid] = (a == bb) ? g : 2.0f*g;
    }
    __syncthreads();

    // ---- D: per-pixel pool -> quantum -> fc -> LN -> ReLU ----
    if (tid < 180) {
        float m[3], cc[3], ssn[3];
        #pragma unroll
        for (int c = 0; c < 3; ++c) {
            m[c] = 0.25f * (xr[c][0].x + xr[c][0].y + xr[c][1].x + xr[c][1].y);
            __sincosf(0.5f*m[c], &ssn[c], &cc[c]);
        }

        float r8[8] = { cc[0]*cc[1]*cc[2], cc[0]*cc[1]*ssn[2],
                        cc[0]*ssn[1]*cc[2], cc[0]*ssn[1]*ssn[2],
                        ssn[0]*cc[1]*cc[2], ssn[0]*cc[1]*ssn[2],
                        ssn[0]*ssn[1]*cc[2], ssn[0]*ssn[1]*ssn[2] };

        float p[36];
        {
            int k = 0;
            #pragma unroll
            for (int a = 0; a < 8; ++a)
                #pragma unroll
                for (int bb = a; bb < 8; ++bb) p[k++] = r8[a]*r8[bb];
        }

        float q[6];
        #pragma unroll
        for (int w = 0; w < 6; ++w) {
            const float4* S4 = reinterpret_cast<const float4*>(Ss + w*36);
            float acc = 0.f;
            #pragma unroll
            for (int j = 0; j < 9; ++j) {
                float4 s4 = S4[j];
                acc += s4.x*p[j*4+0] + s4.y*p[j*4+1]
                     + s4.z*p[j*4+2] + s4.w*p[j*4+3];
            }
            q[w] = acc;
        }

        float y[16]; float mu = 0.f;
        #pragma unroll
        for (int c = 0; c < 16; ++c) {
            float vv = fcbS[c];
            #pragma unroll
            for (int w = 0; w < 6; ++w) vv += fcwS[c*6 + w] * q[w];
            y[c] = vv; mu += vv;
        }
        mu *= 0.0625f;
        float var = 0.f;
        #pragma unroll
        for (int c = 0; c < 16; ++c) { float d = y[c] - mu; var += d*d; }
        var *= 0.0625f;
        float inv = 1.0f / sqrtf(var + 1e-5f);
        #pragma unroll
        for (int c = 0; c < 16; ++c) {
            float vv = (y[c] - mu) * inv * lngS[c] + lnbS[c];
            yS[c][pr][pc] = fmaxf(vv, 0.f);
        }
    }
    __syncthreads();

    // ---- E: bilinear 2x upsample, float4 stores (8 per thread) ----
    #pragma unroll
    for (int k = 0; k < 8; ++k) {
        int it = tid + k * 256;
        int c = it >> 7, rem = it & 127, ohl = rem >> 3, owg = rem & 7;
        int oh = oh0 + ohl, ow = ow0 + owg * 4;
        int kh = oh >> 1, kw = ow >> 1;

        int ha, hb; float wha;
        if (oh & 1) { ha = kh;             hb = min(kh + 1, HP - 1); wha = 0.75f; }
        else        { ha = max(kh - 1, 0); hb = kh;                  wha = 0.25f; }
        ha -= (k0 - 1); hb -= (k0 - 1);
        float whb = 1.f - wha;

        int t0 = max(kw - 1, 0)      - (w0 - 1);
        int t1 = kw                  - (w0 - 1);
        int t2 = kw + 1              - (w0 - 1);
        int t3 = min(kw + 2, WP - 1) - (w0 - 1);

        float va0 = wha * yS[c][ha][t0] + whb * yS[c][hb][t0];
        float va1 = wha * yS[c][ha][t1] + whb * yS[c][hb][t1];
        float va2 = wha * yS[c][ha][t2] + whb * yS[c][hb][t2];
        float va3 = wha * yS[c][ha][t3] + whb * yS[c][hb][t3];

        float4 o;
        o.x = 0.25f * va0 + 0.75f * va1;
        o.y = 0.75f * va1 + 0.25f * va2;
        o.z = 0.25f * va1 + 0.75f * va2;
        o.w = 0.75f * va2 + 0.25f * va3;
        *reinterpret_cast<float4*>(out + (((b*16 + c)*224 + oh)*224 + ow)) = o;
    }
}

extern "C" void kernel_launch(void* const* d_in, const int* in_sizes, int n_in,
                              void* d_out, int out_size, void* d_ws, size_t ws_size,
                              hipStream_t stream) {
    const float* x   = (const float*)d_in[0];
    const float* wts = (const float*)d_in[1];
    const float* fcw = (const float*)d_in[2];
    const float* fcb = (const float*)d_in[3];
    const float* lng = (const float*)d_in[4];
    const float* lnb = (const float*)d_in[5];
    float* out = (float*)d_out;

    fused<<<dim3(7, 14, 8), 256, 0, stream>>>(x, wts, fcw, fcb, lng, lnb, out);
}

// Round 6
// 84.583 us; speedup vs baseline: 1.1236x; 1.1236x over previous
//
#include <hip/hip_runtime.h>
#include <math.h>

// QuantumConv: per-pixel 6-qubit circuit collapses to 6 real symmetric 8x8
// quadratic forms q_w = r^T G_w r (subspace trick: wires 3-5 start at |0>,
// circuit unitary depends only on `weights`). Kernel 1 builds the packed
// symmetrized S[6][36] (triangular, diag x1 / off-diag x2) from the weights;
// kernel 2 fuses pool+quantum+fc+LN+ReLU+bilinear-2x-upsample.
//
// R6: revert to R4 (best-known, 84.5us). R5's single-kernel variant paid the
// circuit-sim prologue per block (784x) = +10.6us — amortizing S via a tiny
// separate dispatch is strictly better.

#define HP 112   // low-res H (=224/2)
#define WP 112

// ---------------- Kernel 1: build S[6][36] from weights ----------------
__global__ __launch_bounds__(512) void build_G(const float* __restrict__ wts,
                                               float* __restrict__ S) {
    __shared__ float  U[24][8];    // per-gate 2x2 complex (re,im): U00 U01 U10 U11
    __shared__ float2 cs[64][9];   // V[s][a] (+1 pad: conflict-free stage-out)
    int t = threadIdx.x;
    int lane = t & 63, wv = t >> 6;   // wave wv owns subspace column a=wv

    if (t < 24) {   // one gate per thread: Rot(phi, theta, omega)
        float phi = wts[t*3+0], th = wts[t*3+1], om = wts[t*3+2];
        float cth, sth, cap, sap, cam, sam;
        sincosf(0.5f*th, &sth, &cth);
        sincosf(0.5f*(phi+om), &sap, &cap);   // ep = cap - i*sap
        sincosf(0.5f*(phi-om), &sam, &cam);   // em = cam - i*sam
        U[t][0] =  cap*cth; U[t][1] = -sap*cth;   // U00 = ep*c
        U[t][2] = -cam*sth; U[t][3] = -sam*sth;   // U01 = -conj(em)*s
        U[t][4] =  cam*sth; U[t][5] = -sam*sth;   // U10 = em*s
        U[t][6] =  cap*cth; U[t][7] =  sap*cth;   // U11 = conj(ep)*c
    }
    __syncthreads();

    // lane = state index; v = amplitude of column wv (basis state wv<<3)
    float2 v = make_float2((lane == (wv << 3)) ? 1.0f : 0.0f, 0.0f);

    for (int l = 0; l < 4; ++l) {
        // single-qubit rotations (wire 0 = MSB, mask 1<<(5-w))
        for (int w = 0; w < 6; ++w) {
            int g = l*6 + w, m = 1 << (5 - w);
            bool hi = (lane & m) != 0;
            float csr = hi ? U[g][6] : U[g][0], csi = hi ? U[g][7] : U[g][1];
            float cpr = hi ? U[g][4] : U[g][2], cpi = hi ? U[g][5] : U[g][3];
            float px = __shfl_xor(v.x, m), py = __shfl_xor(v.y, m);
            v = make_float2(csr*v.x - csi*v.y + cpr*px - cpi*py,
                            csr*v.y + csi*v.x + cpr*py + cpi*px);
        }
        // CNOT ring: control w, target (w+r)%6 — swap target bit where control=1
        int r = l % 5 + 1;
        for (int w = 0; w < 6; ++w) {
            int mc = 1 << (5 - w), mt = 1 << (5 - ((w + r) % 6));
            float px = __shfl_xor(v.x, mt), py = __shfl_xor(v.y, mt);
            if (lane & mc) v = make_float2(px, py);
        }
    }

    cs[lane][wv] = v;
    __syncthreads();

    // G_w[a][b] = Re( i^(pop(a)-pop(b)) * sum_s z_w(s) conj(V[s,a]) V[s,b] )
    // Symmetric in (a,b) -> pack upper triangle, off-diag doubled.
    if (t < 384) {
        int w = t >> 6, a = (t >> 3) & 7, bb = t & 7;
        if (a <= bb) {
            int mw = 1 << (5 - w);
            float re = 0.f, im = 0.f;
            for (int s = 0; s < 64; ++s) {
                float z = (s & mw) ? -1.f : 1.f;
                float2 va = cs[s][a], vb = cs[s][bb];
                re += z * (va.x*vb.x + va.y*vb.y);
                im += z * (va.x*vb.y - va.y*vb.x);
            }
            int d = (__popc(a) - __popc(bb)) & 3;   // conj(f_a)*f_b = i^d
            float g = (d == 0) ? re : (d == 1) ? -im : (d == 2) ? -re : im;
            int idx = 8*a - (a*(a-1))/2 + (bb - a);   // triangular index, 0..35
            S[w*36 + idx] = (a == bb) ? g : 2.0f*g;
        }
    }
}

// ---------------- Kernel 2: fused pool+quantum+fc+LN+ReLU+upsample ----------------
// Block: batch b, 16(oh) x 32(ow) output tile -> needs 10 x 18 low-res y tile.
__global__ __launch_bounds__(256) void fused(
    const float* __restrict__ x, const float* __restrict__ fcw,
    const float* __restrict__ fcb, const float* __restrict__ lng,
    const float* __restrict__ lnb, const float* __restrict__ S,
    float* __restrict__ out) {

    __shared__ __align__(16) float Ss[216];
    __shared__ float fcwS[96], fcbS[16], lngS[16], lnbS[16];
    __shared__ float yS[16][10][18];   // [c][row][col]

    int tid = threadIdx.x;
    int b   = blockIdx.z;
    int ow0 = blockIdx.x * 32, oh0 = blockIdx.y * 16;
    int w0  = blockIdx.x * 16, k0  = blockIdx.y * 8;   // low-res tile origin

    if (tid < 216) Ss[tid] = S[tid];
    for (int i = tid; i < 96;  i += 256) fcwS[i] = fcw[i];
    if (tid < 16) { fcbS[tid] = fcb[tid]; lngS[tid] = lng[tid]; lnbS[tid] = lnb[tid]; }
    __syncthreads();

    if (tid < 180) {   // 10 x 18 low-res pixels (1-halo for bilinear)
        int pr = tid / 18, pc = tid % 18;
        int ih = min(max(k0 - 1 + pr, 0), HP - 1);
        int iw = min(max(w0 - 1 + pc, 0), WP - 1);

        // 2x2 mean pool, 3 channels
        float m[3];
        #pragma unroll
        for (int c = 0; c < 3; ++c) {
            const float2* px = reinterpret_cast<const float2*>(
                x + (((b*3 + c)*224 + 2*ih)*224 + 2*iw));
            float2 r0 = px[0], r1 = px[112];
            m[c] = 0.25f * (r0.x + r0.y + r1.x + r1.y);
        }

        float cc[3], ssn[3];
        #pragma unroll
        for (int c = 0; c < 3; ++c) __sincosf(0.5f*m[c], &ssn[c], &cc[c]);

        float r8[8] = { cc[0]*cc[1]*cc[2], cc[0]*cc[1]*ssn[2],
                        cc[0]*ssn[1]*cc[2], cc[0]*ssn[1]*ssn[2],
                        ssn[0]*cc[1]*cc[2], ssn[0]*cc[1]*ssn[2],
                        ssn[0]*ssn[1]*cc[2], ssn[0]*ssn[1]*ssn[2] };

        // 36 shared products (upper triangle of r r^T)
        float p[36];
        {
            int k = 0;
            #pragma unroll
            for (int a = 0; a < 8; ++a)
                #pragma unroll
                for (int bb = a; bb < 8; ++bb) p[k++] = r8[a]*r8[bb];
        }

        // q_w = dot(S_w, p), 9 x ds_read_b128 per wire
        float q[6];
        #pragma unroll
        for (int w = 0; w < 6; ++w) {
            const float4* S4 = reinterpret_cast<const float4*>(Ss + w*36);
            float acc = 0.f;
            #pragma unroll
            for (int j = 0; j < 9; ++j) {
                float4 s4 = S4[j];
                acc += s4.x*p[j*4+0] + s4.y*p[j*4+1]
                     + s4.z*p[j*4+2] + s4.w*p[j*4+3];
            }
            q[w] = acc;
        }

        // fc -> LayerNorm -> ReLU
        float y[16]; float mu = 0.f;
        #pragma unroll
        for (int c = 0; c < 16; ++c) {
            float v = fcbS[c];
            #pragma unroll
            for (int w = 0; w < 6; ++w) v += fcwS[c*6 + w] * q[w];
            y[c] = v; mu += v;
        }
        mu *= 0.0625f;
        float var = 0.f;
        #pragma unroll
        for (int c = 0; c < 16; ++c) { float d = y[c] - mu; var += d*d; }
        var *= 0.0625f;
        float inv = 1.0f / sqrtf(var + 1e-5f);
        #pragma unroll
        for (int c = 0; c < 16; ++c) {
            float vv = (y[c] - mu) * inv * lngS[c] + lnbS[c];
            yS[c][pr][pc] = fmaxf(vv, 0.f);
        }
    }
    __syncthreads();

    // bilinear 2x upsample, float4 stores. 2048 float4s / 256 threads = 8 each.
    #pragma unroll
    for (int k = 0; k < 8; ++k) {
        int it = tid + k * 256;
        int c = it >> 7, rem = it & 127, ohl = rem >> 3, owg = rem & 7;
        int oh = oh0 + ohl, ow = ow0 + owg * 4;
        int kh = oh >> 1, kw = ow >> 1;

        int ha, hb; float wha;
        if (oh & 1) { ha = kh;             hb = min(kh + 1, HP - 1); wha = 0.75f; }
        else        { ha = max(kh - 1, 0); hb = kh;                  wha = 0.25f; }
        ha -= (k0 - 1); hb -= (k0 - 1);
        float whb = 1.f - wha;

        int t0 = max(kw - 1, 0)      - (w0 - 1);
        int t1 = kw                  - (w0 - 1);
        int t2 = kw + 1              - (w0 - 1);
        int t3 = min(kw + 2, WP - 1) - (w0 - 1);

        float va0 = wha * yS[c][ha][t0] + whb * yS[c][hb][t0];
        float va1 = wha * yS[c][ha][t1] + whb * yS[c][hb][t1];
        float va2 = wha * yS[c][ha][t2] + whb * yS[c][hb][t2];
        float va3 = wha * yS[c][ha][t3] + whb * yS[c][hb][t3];

        float4 o;
        o.x = 0.25f * va0 + 0.75f * va1;
        o.y = 0.75f * va1 + 0.25f * va2;
        o.z = 0.25f * va1 + 0.75f * va2;
        o.w = 0.75f * va2 + 0.25f * va3;
        *reinterpret_cast<float4*>(out + (((b*16 + c)*224 + oh)*224 + ow)) = o;
    }
}

extern "C" void kernel_launch(void* const* d_in, const int* in_sizes, int n_in,
                              void* d_out, int out_size, void* d_ws, size_t ws_size,
                              hipStream_t stream) {
    const float* x   = (const float*)d_in[0];
    const float* wts = (const float*)d_in[1];
    const float* fcw = (const float*)d_in[2];
    const float* fcb = (const float*)d_in[3];
    const float* lng = (const float*)d_in[4];
    const float* lnb = (const float*)d_in[5];
    float* S   = (float*)d_ws;        // 216 floats (packed symmetric G)
    float* out = (float*)d_out;

    build_G<<<1, 512, 0, stream>>>(wts, S);
    fused<<<dim3(7, 14, 8), 256, 0, stream>>>(x, fcw, fcb, lng, lnb, S, out);
}